// Round 5
// baseline (723.156 us; speedup 1.0000x reference)
//
#include <hip/hip_runtime.h>

#define TS 20
#define TS2 400   // 20*20

typedef __attribute__((ext_vector_type(8))) __bf16 bf16x8;
typedef __attribute__((ext_vector_type(4))) __bf16 bf16x4;
typedef __attribute__((ext_vector_type(4))) float  f32x4;
typedef __attribute__((ext_vector_type(4))) int    int4v;

__device__ __forceinline__ float relu_f(float v) { return v > 0.0f ? v : 0.0f; }

#define MFMA16(a, b, c) __builtin_amdgcn_mfma_f32_16x16x32_bf16((a), (b), (c), 0, 0, 0)

// LDS layout for staged planes: [ci-half][L(24x24) padded to 580][8 ci] bf16.
// 16B slot index = cihalf*580 + L: consecutive L -> consecutive slots (conflict-
// free reads); 580 % 8 == 4 makes interleaved 16B writes conflict-free too.
#define LPAD 580

// ---------------------------------------------------------------------------
// Weight packs (unchanged layouts).
// ---------------------------------------------------------------------------
__global__ __launch_bounds__(256)
void pack_w0(const float* __restrict__ w0, __bf16* __restrict__ wpk0)
{
    int idx = blockIdx.x * 256 + (int)threadIdx.x;
    if (idx >= 25 * 32 * 32) return;
    const int c = idx & 31;
    const int m = (idx >> 5) & 31;
    const int e = idx >> 10;
    float v = 0.0f;
    if (c < 25) {
        const int co = m & 15;
        const int k1o = c / 5, k2o = c % 5, k3i = e / 5, k4i = e % 5;
        if (m < 16) v = w0[co * 625 + k1o * 125 + k2o * 25 + k3i * 5 + k4i];
        else        v = w0[co * 625 + k3i * 125 + k4i * 25 + k1o * 5 + k2o];
    }
    wpk0[idx] = (__bf16)v;
}

__global__ __launch_bounds__(256)
void pack_wmid(const float* __restrict__ w10, const float* __restrict__ w11,
               __bf16* __restrict__ wpk)
{
    int idx = blockIdx.x * 256 + (int)threadIdx.x;
    if (idx >= 650 * 512) return;
    const int ci  = idx & 15;
    const int m   = (idx >> 4) & 31;
    const int off = idx >> 9;
    const int inner = off % 26, outer = off / 26;
    const int d1 = outer / 5 - 2, d2 = outer % 5 - 2;
    float v = 0.0f;
    if (inner < 25) {
        const int d3 = inner / 5 - 2, d4 = inner % 5 - 2;
        const int co = m & 7;
        const bool isB  = (m & 8)  != 0;
        const bool is11 = (m & 16) != 0;
        if (is11) {
            int k1, k2, k3, k4;
            if (!isB) { k1 = d1 + 2; k2 = d2 + 2; k3 = d3 + 2; k4 = d4 + 2; }
            else      { k1 = d3 + 2; k2 = d4 + 2; k3 = d1 + 2; k4 = d2 + 2; }
            v = w11[((((co * 16 + ci) * 5 + k1) * 5 + k2) * 5 + k3) * 5 + k4];
        } else {
            if (!isB) {
                if (d1 >= -1 && d1 <= 1 && d2 >= -1 && d2 <= 1)
                    v = w10[((((co * 16 + ci) * 3 + (d1 + 1)) * 3 + (d2 + 1)) * 5 + (d3 + 2)) * 5 + (d4 + 2)];
            } else {
                if (d3 >= -1 && d3 <= 1 && d4 >= -1 && d4 <= 1)
                    v = w10[((((co * 16 + ci) * 3 + (d3 + 1)) * 3 + (d4 + 1)) * 5 + (d1 + 2)) * 5 + (d2 + 2)];
            }
        }
    }
    wpk[idx] = (__bf16)v;
}

__global__ __launch_bounds__(256)
void pack_w2f(const float* __restrict__ w2, __bf16* __restrict__ wpk2f)
{
    int idx = blockIdx.x * 256 + (int)threadIdx.x;
    if (idx >= 26 * 64 * 16) return;
    const int ci = idx & 15;
    const int m  = (idx >> 4) & 63;
    const int e  = idx >> 10;
    float v = 0.0f;
    if (e < 25) {
        if (m < 25)
            v = w2[ci * 625 + (m / 5) * 125 + (m % 5) * 25 + (e / 5) * 5 + (e % 5)];
        else if (m >= 32 && m < 57) {
            const int dd = m - 32;
            v = w2[ci * 625 + (e / 5) * 125 + (e % 5) * 25 + (dd / 5) * 5 + (dd % 5)];
        }
    }
    wpk2f[idx] = (__bf16)v;
}

// ---------------------------------------------------------------------------
// Layer 0 MFMA: virtual channels = 25 outer offsets; conflict-free LDS layout
// [cb 4][LPAD][8c].
// ---------------------------------------------------------------------------
__global__ __launch_bounds__(320)
void conv0_mfma(const float* __restrict__ x, const __bf16* __restrict__ wpk0,
                const float* __restrict__ b0, __bf16* __restrict__ y1)
{
    __shared__ __bf16 lds0[4 * LPAD * 8];   // 37120 B

    const int tid  = (int)threadIdx.x;
    const int lane = tid & 63;
    const int wave = tid >> 6;
    const int bid  = blockIdx.x;
    const int o2 = bid % TS, o1 = (bid / TS) % TS, n = bid / TS2;

    for (int i = tid; i < 4 * LPAD * 8 / 2; i += 320) ((int*)lds0)[i] = 0;
    __syncthreads();

    for (int c = tid; c < 25 * TS2; c += 320) {
        const int pl = c / TS2, pt = c % TS2;
        const int i1 = o1 + pl / 5 - 2, i2 = o2 + pl % 5 - 2;
        if (i1 >= 0 && i1 < TS && i2 >= 0 && i2 < TS) {
            const float v = x[(size_t)((n * TS + i1) * TS + i2) * TS2 + pt];
            const int L = (pt / TS + 2) * 24 + (pt % TS + 2);
            lds0[((pl >> 3) * LPAD + L) * 8 + (pl & 7)] = (__bf16)v;
        }
    }
    __syncthreads();

    const int mrow = lane & 15;
    const int sub  = lane >> 4;

    int sb[5];
#pragma unroll
    for (int i = 0; i < 5; ++i) {
        const int p = (wave * 5 + i) * 16 + mrow;
        sb[i] = (sub * LPAD + (p / TS + 2) * 24 + (p % TS + 2)) * 8;
    }

    f32x4 acc0[5], acc1[5];
#pragma unroll
    for (int i = 0; i < 5; ++i) {
        acc0[i] = (f32x4){0.f, 0.f, 0.f, 0.f};
        acc1[i] = (f32x4){0.f, 0.f, 0.f, 0.f};
    }

    bf16x8 a0 = *(const bf16x8*)(wpk0 + (size_t)mrow * 32 + sub * 8);
    bf16x8 a1 = *(const bf16x8*)(wpk0 + (size_t)(16 + mrow) * 32 + sub * 8);
    for (int e = 0; e < 25; ++e) {
        bf16x8 na0 = a0, na1 = a1;
        if (e < 24) {
            na0 = *(const bf16x8*)(wpk0 + ((size_t)((e + 1) * 32 + mrow)) * 32 + sub * 8);
            na1 = *(const bf16x8*)(wpk0 + ((size_t)((e + 1) * 32 + 16 + mrow)) * 32 + sub * 8);
        }
        const int delta = ((e / 5 - 2) * 24 + (e % 5 - 2)) * 8;
#pragma unroll
        for (int i = 0; i < 5; ++i) {
            bf16x8 bfr = *(const bf16x8*)(&lds0[sb[i] + delta]);
            acc0[i] = MFMA16(a0, bfr, acc0[i]);
            acc1[i] = MFMA16(a1, bfr, acc1[i]);
        }
        a0 = na0; a1 = na1;
    }

    const f32x4 bv = *(const f32x4*)(b0 + sub * 4);
#pragma unroll
    for (int i = 0; i < 5; ++i) {
        const int p = (wave * 5 + i) * 16 + mrow;
        bf16x4 pk;
#pragma unroll
        for (int r = 0; r < 4; ++r)
            pk[r] = (__bf16)(relu_f(acc0[i][r] + bv[r]) + relu_f(acc1[i][r] + bv[r]));
        *(bf16x4*)(y1 + ((size_t)bid * TS2 + p) * 16 + sub * 4) = pk;
    }
}

// ---------------------------------------------------------------------------
// Fused layers 10+11 MFMA.  Block = (n, o1, o2-PAIR): each staged (i1,i2)
// plane's B-frag reads are shared by both o2 outputs (weights differ by d2
// only) -> 2x B-reuse.  Conflict-free LDS [buf 2][cb 2][LPAD][8ci].
// ---------------------------------------------------------------------------
__global__ __launch_bounds__(320)
void conv4d_mid_mfma(const __bf16* __restrict__ y1, const __bf16* __restrict__ wpk,
                     const float* __restrict__ b10, const float* __restrict__ b11,
                     __bf16* __restrict__ y2)
{
    __shared__ __bf16 lds[2][2 * LPAD * 8];   // 2 x 18560 B

    const int tid  = (int)threadIdx.x;
    const int lane = tid & 63;
    const int wave = tid >> 6;
    // XCD swizzle: 800 blocks = 8 XCDs x 100 contiguous tiles (bijective)
    const int bid0 = blockIdx.x;
    const int bid  = (bid0 & 7) * 100 + (bid0 >> 3);
    const int o2p = bid % 10;
    const int o1  = (bid / 10) % TS;
    const int n   = bid / 200;
    const int o2b = o2p * 2;

    for (int i = tid; i < 2 * 2 * LPAD * 8 / 2; i += 320) ((int*)lds)[i] = 0;

    const int mrow = lane & 15;
    const int sub  = lane >> 4;
    const int aoff = (sub >> 1) * 512 + mrow * 16 + (sub & 1) * 8;

    int sbase[5];
#pragma unroll
    for (int i = 0; i < 5; ++i) {
        const int p  = (wave * 5 + i) * 16 + mrow;
        sbase[i] = ((sub & 1) * LPAD + (p / TS + 2) * 24 + (p % TS + 2)) * 8;
    }

    f32x4 acc[2][5][2];
#pragma unroll
    for (int oo = 0; oo < 2; ++oo)
#pragma unroll
        for (int i = 0; i < 5; ++i) {
            acc[oo][i][0] = (f32x4){0.f, 0.f, 0.f, 0.f};
            acc[oo][i][1] = (f32x4){0.f, 0.f, 0.f, 0.f};
        }

    __syncthreads();

    int buf = 0;
    for (int d1 = -2; d1 <= 2; ++d1) {
        const int i1 = o1 + d1;
        if (i1 < 0 || i1 >= TS) continue;
        for (int i2 = o2b - 2; i2 <= o2b + 3; ++i2) {
            if (i2 < 0 || i2 >= TS) continue;
            const int d2a = i2 - o2b;            // in [-2,3]
            const bool va = (d2a <= 2);          // oo=0 valid
            const bool vb = (d2a >= -1);         // oo=1 valid (d2b=d2a-1)

            // stage plane (i1,i2): 800 x 16B, layout [cb][L][8]
            const __bf16* src = y1 + (size_t)((n * TS + i1) * TS + i2) * TS2 * 16;
            for (int c = tid; c < 800; c += 320) {
                const int h = c / 40, rem = c % 40;
                const int w = rem >> 1, cb = rem & 1;
                int4v v = *(const int4v*)(src + c * 8);
                *(int4v*)(&lds[buf][(cb * LPAD + (h + 2) * 24 + 2 + w) * 8]) = v;
            }
            __syncthreads();
            // (single barrier per staging is safe with double buffering)

            const __bf16* wba = wpk + (size_t)((d1 + 2) * 5 + d2a + 2) * 26 * 512;
            const __bf16* wbb = wpk + (size_t)((d1 + 2) * 5 + d2a + 1) * 26 * 512;

            for (int ic = 0; ic < 13; ++ic) {
                bf16x8 a0a{}, a1a{}, a0b{}, a1b{};
                if (va) {
                    a0a = *(const bf16x8*)(wba + ic * 1024 + aoff);
                    a1a = *(const bf16x8*)(wba + ic * 1024 + aoff + 256);
                }
                if (vb) {
                    a0b = *(const bf16x8*)(wbb + ic * 1024 + aoff);
                    a1b = *(const bf16x8*)(wbb + ic * 1024 + aoff + 256);
                }
                const int e = 2 * ic + (sub >> 1);
                int d3 = 0, d4 = 0;
                if (e < 25) { d3 = e / 5 - 2; d4 = e % 5 - 2; }
                const int delta = (d3 * 24 + d4) * 8;
#pragma unroll
                for (int i = 0; i < 5; ++i) {
                    bf16x8 bfr = *(const bf16x8*)(&lds[buf][sbase[i] + delta]);
                    if (va) {
                        acc[0][i][0] = MFMA16(a0a, bfr, acc[0][i][0]);
                        acc[0][i][1] = MFMA16(a1a, bfr, acc[0][i][1]);
                    }
                    if (vb) {
                        acc[1][i][0] = MFMA16(a0b, bfr, acc[1][i][0]);
                        acc[1][i][1] = MFMA16(a1b, bfr, acc[1][i][1]);
                    }
                }
            }
            buf ^= 1;
        }
    }

    // epilogue -> interleaved bf16 [p][ch]; combine A/B variants via lane^32
#pragma unroll
    for (int oo = 0; oo < 2; ++oo) {
        const size_t base = ((size_t)((n * TS + o1) * TS + (o2b + oo))) * (size_t)TS2 * 16;
#pragma unroll
        for (int i = 0; i < 5; ++i) {
            const int p = (wave * 5 + i) * 16 + mrow;
#pragma unroll
            for (int mt = 0; mt < 2; ++mt) {
                const float* bs = mt ? b11 : b10;
                const f32x4 bv = *(const f32x4*)(bs + (sub & 1) * 4);
                bf16x4 pk;
#pragma unroll
                for (int r = 0; r < 4; ++r) {
                    float v = relu_f(acc[oo][i][mt][r] + bv[r]);
                    float o = v + __shfl_xor(v, 32);
                    pk[r] = (__bf16)o;
                }
                if (lane < 32)
                    *(bf16x4*)(y2 + base + (size_t)p * 16 + mt * 8 + (sub & 1) * 4) = pk;
            }
        }
    }
}

// ---------------------------------------------------------------------------
// Layer 2 pass 1: t[q, m] = sum_{di,ci} wpk2f[di][m][ci] * y2[q, .+di, ci].
// M = 64 (50 real), K = 26x16; one staging per block; conflict-free layout.
// ---------------------------------------------------------------------------
__global__ __launch_bounds__(320)
void conv2t_mfma(const __bf16* __restrict__ y2, const __bf16* __restrict__ wpk2f,
                 int n0, __bf16* __restrict__ t)
{
    __shared__ __bf16 lds[2 * LPAD * 8];

    const int tid  = (int)threadIdx.x;
    const int lane = tid & 63;
    const int wave = tid >> 6;
    const int bid = blockIdx.x;
    const int q2 = bid % TS, q1 = (bid / TS) % TS, nl = bid / TS2;

    for (int i = tid; i < 2 * LPAD * 8 / 2; i += 320) ((int*)lds)[i] = 0;
    __syncthreads();

    const __bf16* src = y2 + (size_t)(((n0 + nl) * TS + q1) * TS + q2) * TS2 * 16;
    for (int c = tid; c < 800; c += 320) {
        const int h = c / 40, rem = c % 40;
        const int w = rem >> 1, cb = rem & 1;
        int4v v = *(const int4v*)(src + c * 8);
        *(int4v*)(&lds[(cb * LPAD + (h + 2) * 24 + 2 + w) * 8]) = v;
    }
    __syncthreads();

    const int mrow = lane & 15;
    const int sub  = lane >> 4;

    int sbase[5];
#pragma unroll
    for (int i = 0; i < 5; ++i) {
        const int p  = (wave * 5 + i) * 16 + mrow;
        sbase[i] = ((sub & 1) * LPAD + (p / TS + 2) * 24 + (p % TS + 2)) * 8;
    }

    f32x4 acc[5][4];
#pragma unroll
    for (int i = 0; i < 5; ++i)
#pragma unroll
        for (int mt = 0; mt < 4; ++mt)
            acc[i][mt] = (f32x4){0.f, 0.f, 0.f, 0.f};

    for (int ic = 0; ic < 13; ++ic) {
        const int e = 2 * ic + (sub >> 1);
        int d3 = 0, d4 = 0;
        if (e < 25) { d3 = e / 5 - 2; d4 = e % 5 - 2; }
        const int delta = (d3 * 24 + d4) * 8;
        const __bf16* abase = wpk2f + ((size_t)e * 64 + mrow) * 16 + (sub & 1) * 8;
        bf16x8 a0 = *(const bf16x8*)(abase);
        bf16x8 a1 = *(const bf16x8*)(abase + 256);
        bf16x8 a2 = *(const bf16x8*)(abase + 512);
        bf16x8 a3 = *(const bf16x8*)(abase + 768);
#pragma unroll
        for (int i = 0; i < 5; ++i) {
            bf16x8 bfr = *(const bf16x8*)(&lds[sbase[i] + delta]);
            acc[i][0] = MFMA16(a0, bfr, acc[i][0]);
            acc[i][1] = MFMA16(a1, bfr, acc[i][1]);
            acc[i][2] = MFMA16(a2, bfr, acc[i][2]);
            acc[i][3] = MFMA16(a3, bfr, acc[i][3]);
        }
    }

    __bf16* tb = t + (size_t)((nl * TS + q1) * TS + q2) * (50 * TS2);
#pragma unroll
    for (int i = 0; i < 5; ++i) {
        const int p = (wave * 5 + i) * 16 + mrow;
#pragma unroll
        for (int mt = 0; mt < 4; ++mt) {
#pragma unroll
            for (int r = 0; r < 4; ++r) {
                const int gm = mt * 16 + sub * 4 + r;
                int m50 = -1;
                if (gm < 25) m50 = gm;
                else if (gm >= 32 && gm < 57) m50 = gm - 7;
                if (m50 >= 0) tb[m50 * TS2 + p] = (__bf16)acc[i][mt][r];
            }
        }
    }
}

// ---------------------------------------------------------------------------
// Layer 2 pass 2: gather-sum over 25 outer offsets + bias + ReLU.
// ---------------------------------------------------------------------------
__global__ __launch_bounds__(448)
void conv2_sum(const __bf16* __restrict__ t, const float* __restrict__ b2,
               int n0, float* __restrict__ out)
{
    const int tid = (int)threadIdx.x;
    if (tid >= TS2) return;
    const int bid = blockIdx.x;
    const int o2 = bid % TS, o1 = (bid / TS) % TS, nl = bid / TS2;

    float accA = 0.0f, accB = 0.0f;
    for (int dd = 0; dd < 25; ++dd) {
        const int q1 = o1 + dd / 5 - 2, q2 = o2 + dd % 5 - 2;
        if (q1 < 0 || q1 >= TS || q2 < 0 || q2 >= TS) continue;
        const __bf16* tb = t + (size_t)((nl * TS + q1) * TS + q2) * (50 * TS2) + tid;
        accA += (float)tb[dd * TS2];
        accB += (float)tb[(25 + dd) * TS2];
    }
    const float bias = b2[0];
    out[(size_t)(n0 + nl) * (TS2 * (size_t)TS2) + (size_t)(o1 * TS + o2) * TS2 + tid] =
        relu_f(accA + bias) + relu_f(accB + bias);
}

// ---------------------------------------------------------------------------
extern "C" void kernel_launch(void* const* d_in, const int* in_sizes, int n_in,
                              void* d_out, int out_size, void* d_ws, size_t ws_size,
                              hipStream_t stream)
{
    const float* x   = (const float*)d_in[0];
    const float* w0  = (const float*)d_in[1];
    const float* b0  = (const float*)d_in[2];
    const float* w10 = (const float*)d_in[3];
    const float* b10 = (const float*)d_in[4];
    const float* w11 = (const float*)d_in[5];
    const float* b11 = (const float*)d_in[6];
    const float* w2  = (const float*)d_in[7];
    const float* b2  = (const float*)d_in[8];
    float* out = (float*)d_out;

    // ws: y1 20.5MB | y2 20.5MB | t 32MB (2-image chunk) | packs ~0.8MB
    __bf16* y1    = (__bf16*)d_ws;
    __bf16* y2    = y1 + (size_t)10240000;
    __bf16* tbuf  = y2 + (size_t)10240000;
    __bf16* wpkm  = tbuf + (size_t)16000000;
    __bf16* wpk0  = wpkm + 650 * 512;
    __bf16* wpk2f = wpk0 + 25 * 32 * 32;

    dim3 blk320(320), blk256(256), blk448(448);

    pack_w0  <<<dim3((25600 + 255) / 256),  blk256, 0, stream>>>(w0, wpk0);
    pack_wmid<<<dim3((332800 + 255) / 256), blk256, 0, stream>>>(w10, w11, wpkm);
    pack_w2f <<<dim3((26624 + 255) / 256),  blk256, 0, stream>>>(w2, wpk2f);

    conv0_mfma     <<<dim3(4 * TS * TS), blk320, 0, stream>>>(x, wpk0, b0, y1);
    conv4d_mid_mfma<<<dim3(800),         blk320, 0, stream>>>(y1, wpkm, b10, b11, y2);

    for (int n0 = 0; n0 < 4; n0 += 2) {
        conv2t_mfma<<<dim3(800), blk320, 0, stream>>>(y2, wpk2f, n0, tbuf);
        conv2_sum  <<<dim3(800), blk448, 0, stream>>>(tbuf, b2, n0, out);
    }
}

// Round 6
// 682.657 us; speedup vs baseline: 1.0593x; 1.0593x over previous
//
#include <hip/hip_runtime.h>

#define TS 20
#define TS2 400   // 20*20

typedef __attribute__((ext_vector_type(8))) __bf16 bf16x8;
typedef __attribute__((ext_vector_type(4))) __bf16 bf16x4;
typedef __attribute__((ext_vector_type(4))) float  f32x4;
typedef __attribute__((ext_vector_type(4))) int    int4v;

__device__ __forceinline__ float relu_f(float v) { return v > 0.0f ? v : 0.0f; }

#define MFMA16(a, b, c) __builtin_amdgcn_mfma_f32_16x16x32_bf16((a), (b), (c), 0, 0, 0)

#define LPAD 580   // conv0/conv2t staging layout (unchanged from round 5)

// ---------------------------------------------------------------------------
// Weight packs (unchanged).
// ---------------------------------------------------------------------------
__global__ __launch_bounds__(256)
void pack_w0(const float* __restrict__ w0, __bf16* __restrict__ wpk0)
{
    int idx = blockIdx.x * 256 + (int)threadIdx.x;
    if (idx >= 25 * 32 * 32) return;
    const int c = idx & 31;
    const int m = (idx >> 5) & 31;
    const int e = idx >> 10;
    float v = 0.0f;
    if (c < 25) {
        const int co = m & 15;
        const int k1o = c / 5, k2o = c % 5, k3i = e / 5, k4i = e % 5;
        if (m < 16) v = w0[co * 625 + k1o * 125 + k2o * 25 + k3i * 5 + k4i];
        else        v = w0[co * 625 + k3i * 125 + k4i * 25 + k1o * 5 + k2o];
    }
    wpk0[idx] = (__bf16)v;
}

__global__ __launch_bounds__(256)
void pack_wmid(const float* __restrict__ w10, const float* __restrict__ w11,
               __bf16* __restrict__ wpk)
{
    int idx = blockIdx.x * 256 + (int)threadIdx.x;
    if (idx >= 650 * 512) return;
    const int ci  = idx & 15;
    const int m   = (idx >> 4) & 31;
    const int off = idx >> 9;
    const int inner = off % 26, outer = off / 26;
    const int d1 = outer / 5 - 2, d2 = outer % 5 - 2;
    float v = 0.0f;
    if (inner < 25) {
        const int d3 = inner / 5 - 2, d4 = inner % 5 - 2;
        const int co = m & 7;
        const bool isB  = (m & 8)  != 0;
        const bool is11 = (m & 16) != 0;
        if (is11) {
            int k1, k2, k3, k4;
            if (!isB) { k1 = d1 + 2; k2 = d2 + 2; k3 = d3 + 2; k4 = d4 + 2; }
            else      { k1 = d3 + 2; k2 = d4 + 2; k3 = d1 + 2; k4 = d2 + 2; }
            v = w11[((((co * 16 + ci) * 5 + k1) * 5 + k2) * 5 + k3) * 5 + k4];
        } else {
            if (!isB) {
                if (d1 >= -1 && d1 <= 1 && d2 >= -1 && d2 <= 1)
                    v = w10[((((co * 16 + ci) * 3 + (d1 + 1)) * 3 + (d2 + 1)) * 5 + (d3 + 2)) * 5 + (d4 + 2)];
            } else {
                if (d3 >= -1 && d3 <= 1 && d4 >= -1 && d4 <= 1)
                    v = w10[((((co * 16 + ci) * 3 + (d3 + 1)) * 3 + (d4 + 1)) * 5 + (d1 + 2)) * 5 + (d2 + 2)];
            }
        }
    }
    wpk[idx] = (__bf16)v;
}

__global__ __launch_bounds__(256)
void pack_w2f(const float* __restrict__ w2, __bf16* __restrict__ wpk2f)
{
    int idx = blockIdx.x * 256 + (int)threadIdx.x;
    if (idx >= 26 * 64 * 16) return;
    const int ci = idx & 15;
    const int m  = (idx >> 4) & 63;
    const int e  = idx >> 10;
    float v = 0.0f;
    if (e < 25) {
        if (m < 25)
            v = w2[ci * 625 + (m / 5) * 125 + (m % 5) * 25 + (e / 5) * 5 + (e % 5)];
        else if (m >= 32 && m < 57) {
            const int dd = m - 32;
            v = w2[ci * 625 + (e / 5) * 125 + (e % 5) * 25 + (dd / 5) * 5 + (dd % 5)];
        }
    }
    wpk2f[idx] = (__bf16)v;
}

// ---------------------------------------------------------------------------
// Layer 0 MFMA (unchanged from round 5).
// ---------------------------------------------------------------------------
__global__ __launch_bounds__(320)
void conv0_mfma(const float* __restrict__ x, const __bf16* __restrict__ wpk0,
                const float* __restrict__ b0, __bf16* __restrict__ y1)
{
    __shared__ __bf16 lds0[4 * LPAD * 8];

    const int tid  = (int)threadIdx.x;
    const int lane = tid & 63;
    const int wave = tid >> 6;
    const int bid  = blockIdx.x;
    const int o2 = bid % TS, o1 = (bid / TS) % TS, n = bid / TS2;

    for (int i = tid; i < 4 * LPAD * 8 / 2; i += 320) ((int*)lds0)[i] = 0;
    __syncthreads();

    for (int c = tid; c < 25 * TS2; c += 320) {
        const int pl = c / TS2, pt = c % TS2;
        const int i1 = o1 + pl / 5 - 2, i2 = o2 + pl % 5 - 2;
        if (i1 >= 0 && i1 < TS && i2 >= 0 && i2 < TS) {
            const float v = x[(size_t)((n * TS + i1) * TS + i2) * TS2 + pt];
            const int L = (pt / TS + 2) * 24 + (pt % TS + 2);
            lds0[((pl >> 3) * LPAD + L) * 8 + (pl & 7)] = (__bf16)v;
        }
    }
    __syncthreads();

    const int mrow = lane & 15;
    const int sub  = lane >> 4;

    int sb[5];
#pragma unroll
    for (int i = 0; i < 5; ++i) {
        const int p = (wave * 5 + i) * 16 + mrow;
        sb[i] = (sub * LPAD + (p / TS + 2) * 24 + (p % TS + 2)) * 8;
    }

    f32x4 acc0[5], acc1[5];
#pragma unroll
    for (int i = 0; i < 5; ++i) {
        acc0[i] = (f32x4){0.f, 0.f, 0.f, 0.f};
        acc1[i] = (f32x4){0.f, 0.f, 0.f, 0.f};
    }

    bf16x8 a0 = *(const bf16x8*)(wpk0 + (size_t)mrow * 32 + sub * 8);
    bf16x8 a1 = *(const bf16x8*)(wpk0 + (size_t)(16 + mrow) * 32 + sub * 8);
    for (int e = 0; e < 25; ++e) {
        bf16x8 na0 = a0, na1 = a1;
        if (e < 24) {
            na0 = *(const bf16x8*)(wpk0 + ((size_t)((e + 1) * 32 + mrow)) * 32 + sub * 8);
            na1 = *(const bf16x8*)(wpk0 + ((size_t)((e + 1) * 32 + 16 + mrow)) * 32 + sub * 8);
        }
        const int delta = ((e / 5 - 2) * 24 + (e % 5 - 2)) * 8;
#pragma unroll
        for (int i = 0; i < 5; ++i) {
            bf16x8 bfr = *(const bf16x8*)(&lds0[sb[i] + delta]);
            acc0[i] = MFMA16(a0, bfr, acc0[i]);
            acc1[i] = MFMA16(a1, bfr, acc1[i]);
        }
        a0 = na0; a1 = na1;
    }

    const f32x4 bv = *(const f32x4*)(b0 + sub * 4);
#pragma unroll
    for (int i = 0; i < 5; ++i) {
        const int p = (wave * 5 + i) * 16 + mrow;
        bf16x4 pk;
#pragma unroll
        for (int r = 0; r < 4; ++r)
            pk[r] = (__bf16)(relu_f(acc0[i][r] + bv[r]) + relu_f(acc1[i][r] + bv[r]));
        *(bf16x4*)(y1 + ((size_t)bid * TS2 + p) * 16 + sub * 4) = pk;
    }
}

// ---------------------------------------------------------------------------
// Fused layers 10+11 MFMA, o2-PAIR v2:
//  - each staged (i1,i2) plane's B-reads feed BOTH o2 outputs (2x fewer DS
//    bytes per FLOP; kernel is DS-read-throughput-bound)
//  - SINGLE 18.4 KB LDS buffer, round-3 [L][16ci] layout
//  - T14 staging: global loads for the next plane issue before compute,
//    reg->LDS write happens after the post-compute barrier (latency hidden)
// ---------------------------------------------------------------------------
__global__ __launch_bounds__(320)
void conv4d_mid_mfma(const __bf16* __restrict__ y1, const __bf16* __restrict__ wpk,
                     const float* __restrict__ b10, const float* __restrict__ b11,
                     __bf16* __restrict__ y2)
{
    __shared__ __bf16 lds[9216];   // [24*24][16ci] = 18432 B, single buffer

    const int tid  = (int)threadIdx.x;
    const int lane = tid & 63;
    const int wave = tid >> 6;
    // XCD swizzle: 800 blocks = 8 XCDs x 100 contiguous tiles (bijective)
    const int bid0 = blockIdx.x;
    const int bid  = (bid0 & 7) * 100 + (bid0 >> 3);
    const int o2p = bid % 10;
    const int o1  = (bid / 10) % TS;
    const int n   = bid / 200;
    const int o2b = o2p * 2;

    for (int i = tid; i < 4608; i += 320) ((int*)lds)[i] = 0;

    const int mrow = lane & 15;
    const int sub  = lane >> 4;
    const int ci0  = (sub & 1) * 8;
    const int aoff = (sub >> 1) * 512 + mrow * 16 + ci0;

    int sbase[5];
#pragma unroll
    for (int i = 0; i < 5; ++i) {
        const int p  = (wave * 5 + i) * 16 + mrow;
        sbase[i] = ((p / TS + 2) * 24 + (p % TS + 2)) * 16 + ci0;
    }

    f32x4 acc[2][5][2];
#pragma unroll
    for (int oo = 0; oo < 2; ++oo)
#pragma unroll
        for (int i = 0; i < 5; ++i) {
            acc[oo][i][0] = (f32x4){0.f, 0.f, 0.f, 0.f};
            acc[oo][i][1] = (f32x4){0.f, 0.f, 0.f, 0.f};
        }

    // staging iteration space: kk = (d1+2)*6 + (i2-(o2b-2)), kk in [0,30)
    // validity is block-uniform.
    const int c2ok = (tid < 160);
    int4v sreg0, sreg1, sreg2;

    // find first valid kk and issue its loads
    int kk = 0;
    for (;;) {
        const int i1 = o1 + kk / 6 - 2, i2 = o2b + kk % 6 - 2;
        if (i1 >= 0 && i1 < TS && i2 >= 0 && i2 < TS) break;
        ++kk;   // (o1,o2b interior of grid guarantees kk<30 terminates with >=20 valid)
    }
    {
        const int i1 = o1 + kk / 6 - 2, i2 = o2b + kk % 6 - 2;
        const __bf16* src = y1 + (size_t)((n * TS + i1) * TS + i2) * TS2 * 16;
        sreg0 = *(const int4v*)(src + (size_t)tid * 8);
        sreg1 = *(const int4v*)(src + (size_t)(tid + 320) * 8);
        if (c2ok) sreg2 = *(const int4v*)(src + (size_t)(tid + 640) * 8);
    }
    __syncthreads();   // zero-init complete

    while (kk < 30) {
        // ---- write current plane regs -> LDS (loads landed during prev compute)
        {
            int c = tid, rem = c % 40, h = c / 40;
            *(int4v*)(&lds[((h + 2) * 24 + 2) * 16 + rem * 8]) = sreg0;
            c = tid + 320; rem = c % 40; h = c / 40;
            *(int4v*)(&lds[((h + 2) * 24 + 2) * 16 + rem * 8]) = sreg1;
            if (c2ok) {
                c = tid + 640; rem = c % 40; h = c / 40;
                *(int4v*)(&lds[((h + 2) * 24 + 2) * 16 + rem * 8]) = sreg2;
            }
        }
        __syncthreads();   // plane visible

        // ---- issue next valid plane's loads (hidden under compute below)
        int nk = kk + 1;
        while (nk < 30) {
            const int i1 = o1 + nk / 6 - 2, i2 = o2b + nk % 6 - 2;
            if (i1 >= 0 && i1 < TS && i2 >= 0 && i2 < TS) break;
            ++nk;
        }
        if (nk < 30) {
            const int i1 = o1 + nk / 6 - 2, i2 = o2b + nk % 6 - 2;
            const __bf16* src = y1 + (size_t)((n * TS + i1) * TS + i2) * TS2 * 16;
            sreg0 = *(const int4v*)(src + (size_t)tid * 8);
            sreg1 = *(const int4v*)(src + (size_t)(tid + 320) * 8);
            if (c2ok) sreg2 = *(const int4v*)(src + (size_t)(tid + 640) * 8);
        }

        // ---- compute plane kk for both o2 outputs
        const int d1  = kk / 6 - 2;
        const int d2a = kk % 6 - 2;                 // offset for output o2b, in [-2,3]
        const bool va = (d2a <= 2);
        const bool vb = (d2a >= -1);                // output o2b+1 offset = d2a-1
        const int oa = (d1 + 2) * 5 + (va ? d2a + 2 : 0);
        const int ob = (d1 + 2) * 5 + (vb ? d2a + 1 : 0);
        const __bf16* wba = wpk + (size_t)oa * 26 * 512;
        const __bf16* wbb = wpk + (size_t)ob * 26 * 512;

        bf16x8 a0a{}, a1a{}, a0b{}, a1b{};
        if (va) { a0a = *(const bf16x8*)(wba + aoff); a1a = *(const bf16x8*)(wba + aoff + 256); }
        if (vb) { a0b = *(const bf16x8*)(wbb + aoff); a1b = *(const bf16x8*)(wbb + aoff + 256); }
        for (int ic = 0; ic < 13; ++ic) {
            bf16x8 n0a = a0a, n1a = a1a, n0b = a0b, n1b = a1b;
            if (ic < 12) {
                if (va) {
                    n0a = *(const bf16x8*)(wba + (ic + 1) * 1024 + aoff);
                    n1a = *(const bf16x8*)(wba + (ic + 1) * 1024 + aoff + 256);
                }
                if (vb) {
                    n0b = *(const bf16x8*)(wbb + (ic + 1) * 1024 + aoff);
                    n1b = *(const bf16x8*)(wbb + (ic + 1) * 1024 + aoff + 256);
                }
            }
            const int e = 2 * ic + (sub >> 1);
            int d3 = 0, d4 = 0;
            if (e < 25) { d3 = e / 5 - 2; d4 = e % 5 - 2; }
            const int delta = (d3 * 24 + d4) * 16;
#pragma unroll
            for (int i = 0; i < 5; ++i) {
                bf16x8 bfr = *(const bf16x8*)(&lds[sbase[i] + delta]);
                if (va) {
                    acc[0][i][0] = MFMA16(a0a, bfr, acc[0][i][0]);
                    acc[0][i][1] = MFMA16(a1a, bfr, acc[0][i][1]);
                }
                if (vb) {
                    acc[1][i][0] = MFMA16(a0b, bfr, acc[1][i][0]);
                    acc[1][i][1] = MFMA16(a1b, bfr, acc[1][i][1]);
                }
            }
            a0a = n0a; a1a = n1a; a0b = n0b; a1b = n1b;
        }

        __syncthreads();   // all waves done reading before next overwrite
        kk = nk;
    }

    // ---- epilogue -> interleaved bf16 [p][ch]; combine A/B variants via lane^32
#pragma unroll
    for (int oo = 0; oo < 2; ++oo) {
        const size_t base = ((size_t)((n * TS + o1) * TS + (o2b + oo))) * (size_t)TS2 * 16;
#pragma unroll
        for (int i = 0; i < 5; ++i) {
            const int p = (wave * 5 + i) * 16 + mrow;
#pragma unroll
            for (int mt = 0; mt < 2; ++mt) {
                const float* bs = mt ? b11 : b10;
                const f32x4 bv = *(const f32x4*)(bs + (sub & 1) * 4);
                bf16x4 pk;
#pragma unroll
                for (int r = 0; r < 4; ++r) {
                    float v = relu_f(acc[oo][i][mt][r] + bv[r]);
                    float o = v + __shfl_xor(v, 32);
                    pk[r] = (__bf16)o;
                }
                if (lane < 32)
                    *(bf16x4*)(y2 + base + (size_t)p * 16 + mt * 8 + (sub & 1) * 4) = pk;
            }
        }
    }
}

// ---------------------------------------------------------------------------
// Layer 2 pass 1 (unchanged from round 5).
// ---------------------------------------------------------------------------
__global__ __launch_bounds__(320)
void conv2t_mfma(const __bf16* __restrict__ y2, const __bf16* __restrict__ wpk2f,
                 int n0, __bf16* __restrict__ t)
{
    __shared__ __bf16 lds[2 * LPAD * 8];

    const int tid  = (int)threadIdx.x;
    const int lane = tid & 63;
    const int wave = tid >> 6;
    const int bid = blockIdx.x;
    const int q2 = bid % TS, q1 = (bid / TS) % TS, nl = bid / TS2;

    for (int i = tid; i < 2 * LPAD * 8 / 2; i += 320) ((int*)lds)[i] = 0;
    __syncthreads();

    const __bf16* src = y2 + (size_t)(((n0 + nl) * TS + q1) * TS + q2) * TS2 * 16;
    for (int c = tid; c < 800; c += 320) {
        const int h = c / 40, rem = c % 40;
        const int w = rem >> 1, cb = rem & 1;
        int4v v = *(const int4v*)(src + c * 8);
        *(int4v*)(&lds[(cb * LPAD + (h + 2) * 24 + 2 + w) * 8]) = v;
    }
    __syncthreads();

    const int mrow = lane & 15;
    const int sub  = lane >> 4;

    int sbase[5];
#pragma unroll
    for (int i = 0; i < 5; ++i) {
        const int p  = (wave * 5 + i) * 16 + mrow;
        sbase[i] = ((sub & 1) * LPAD + (p / TS + 2) * 24 + (p % TS + 2)) * 8;
    }

    f32x4 acc[5][4];
#pragma unroll
    for (int i = 0; i < 5; ++i)
#pragma unroll
        for (int mt = 0; mt < 4; ++mt)
            acc[i][mt] = (f32x4){0.f, 0.f, 0.f, 0.f};

    for (int ic = 0; ic < 13; ++ic) {
        const int e = 2 * ic + (sub >> 1);
        int d3 = 0, d4 = 0;
        if (e < 25) { d3 = e / 5 - 2; d4 = e % 5 - 2; }
        const int delta = (d3 * 24 + d4) * 8;
        const __bf16* abase = wpk2f + ((size_t)e * 64 + mrow) * 16 + (sub & 1) * 8;
        bf16x8 a0 = *(const bf16x8*)(abase);
        bf16x8 a1 = *(const bf16x8*)(abase + 256);
        bf16x8 a2 = *(const bf16x8*)(abase + 512);
        bf16x8 a3 = *(const bf16x8*)(abase + 768);
#pragma unroll
        for (int i = 0; i < 5; ++i) {
            bf16x8 bfr = *(const bf16x8*)(&lds[sbase[i] + delta]);
            acc[i][0] = MFMA16(a0, bfr, acc[i][0]);
            acc[i][1] = MFMA16(a1, bfr, acc[i][1]);
            acc[i][2] = MFMA16(a2, bfr, acc[i][2]);
            acc[i][3] = MFMA16(a3, bfr, acc[i][3]);
        }
    }

    __bf16* tb = t + (size_t)((nl * TS + q1) * TS + q2) * (50 * TS2);
#pragma unroll
    for (int i = 0; i < 5; ++i) {
        const int p = (wave * 5 + i) * 16 + mrow;
#pragma unroll
        for (int mt = 0; mt < 4; ++mt) {
#pragma unroll
            for (int r = 0; r < 4; ++r) {
                const int gm = mt * 16 + sub * 4 + r;
                int m50 = -1;
                if (gm < 25) m50 = gm;
                else if (gm >= 32 && gm < 57) m50 = gm - 7;
                if (m50 >= 0) tb[m50 * TS2 + p] = (__bf16)acc[i][mt][r];
            }
        }
    }
}

// ---------------------------------------------------------------------------
// Layer 2 pass 2 (unchanged).
// ---------------------------------------------------------------------------
__global__ __launch_bounds__(448)
void conv2_sum(const __bf16* __restrict__ t, const float* __restrict__ b2,
               int n0, float* __restrict__ out)
{
    const int tid = (int)threadIdx.x;
    if (tid >= TS2) return;
    const int bid = blockIdx.x;
    const int o2 = bid % TS, o1 = (bid / TS) % TS, nl = bid / TS2;

    float accA = 0.0f, accB = 0.0f;
    for (int dd = 0; dd < 25; ++dd) {
        const int q1 = o1 + dd / 5 - 2, q2 = o2 + dd % 5 - 2;
        if (q1 < 0 || q1 >= TS || q2 < 0 || q2 >= TS) continue;
        const __bf16* tb = t + (size_t)((nl * TS + q1) * TS + q2) * (50 * TS2) + tid;
        accA += (float)tb[dd * TS2];
        accB += (float)tb[(25 + dd) * TS2];
    }
    const float bias = b2[0];
    out[(size_t)(n0 + nl) * (TS2 * (size_t)TS2) + (size_t)(o1 * TS + o2) * TS2 + tid] =
        relu_f(accA + bias) + relu_f(accB + bias);
}

// ---------------------------------------------------------------------------
extern "C" void kernel_launch(void* const* d_in, const int* in_sizes, int n_in,
                              void* d_out, int out_size, void* d_ws, size_t ws_size,
                              hipStream_t stream)
{
    const float* x   = (const float*)d_in[0];
    const float* w0  = (const float*)d_in[1];
    const float* b0  = (const float*)d_in[2];
    const float* w10 = (const float*)d_in[3];
    const float* b10 = (const float*)d_in[4];
    const float* w11 = (const float*)d_in[5];
    const float* b11 = (const float*)d_in[6];
    const float* w2  = (const float*)d_in[7];
    const float* b2  = (const float*)d_in[8];
    float* out = (float*)d_out;

    // ws: y1 20.5MB | y2 20.5MB | t 32MB (2-image chunk) | packs ~0.8MB
    __bf16* y1    = (__bf16*)d_ws;
    __bf16* y2    = y1 + (size_t)10240000;
    __bf16* tbuf  = y2 + (size_t)10240000;
    __bf16* wpkm  = tbuf + (size_t)16000000;
    __bf16* wpk0  = wpkm + 650 * 512;
    __bf16* wpk2f = wpk0 + 25 * 32 * 32;

    dim3 blk320(320), blk256(256), blk448(448);

    pack_w0  <<<dim3((25600 + 255) / 256),  blk256, 0, stream>>>(w0, wpk0);
    pack_wmid<<<dim3((332800 + 255) / 256), blk256, 0, stream>>>(w10, w11, wpkm);
    pack_w2f <<<dim3((26624 + 255) / 256),  blk256, 0, stream>>>(w2, wpk2f);

    conv0_mfma     <<<dim3(4 * TS * TS), blk320, 0, stream>>>(x, wpk0, b0, y1);
    conv4d_mid_mfma<<<dim3(800),         blk320, 0, stream>>>(y1, wpkm, b10, b11, y2);

    for (int n0 = 0; n0 < 4; n0 += 2) {
        conv2t_mfma<<<dim3(800), blk320, 0, stream>>>(y2, wpk2f, n0, tbuf);
        conv2_sum  <<<dim3(800), blk448, 0, stream>>>(tbuf, b2, n0, out);
    }
}

// Round 7
// 483.497 us; speedup vs baseline: 1.4957x; 1.4119x over previous
//
#include <hip/hip_runtime.h>

#define TS 20
#define TS2 400   // 20*20

typedef __attribute__((ext_vector_type(8))) __bf16 bf16x8;
typedef __attribute__((ext_vector_type(4))) __bf16 bf16x4;
typedef __attribute__((ext_vector_type(4))) float  f32x4;
typedef __attribute__((ext_vector_type(4))) int    int4v;

__device__ __forceinline__ float relu_f(float v) { return v > 0.0f ? v : 0.0f; }

#define MFMA16(a, b, c) __builtin_amdgcn_mfma_f32_16x16x32_bf16((a), (b), (c), 0, 0, 0)

#define LPAD 580   // conv0/conv2t staging layout

// ---------------------------------------------------------------------------
// Weight packs (unchanged).
// ---------------------------------------------------------------------------
__global__ __launch_bounds__(256)
void pack_w0(const float* __restrict__ w0, __bf16* __restrict__ wpk0)
{
    int idx = blockIdx.x * 256 + (int)threadIdx.x;
    if (idx >= 25 * 32 * 32) return;
    const int c = idx & 31;
    const int m = (idx >> 5) & 31;
    const int e = idx >> 10;
    float v = 0.0f;
    if (c < 25) {
        const int co = m & 15;
        const int k1o = c / 5, k2o = c % 5, k3i = e / 5, k4i = e % 5;
        if (m < 16) v = w0[co * 625 + k1o * 125 + k2o * 25 + k3i * 5 + k4i];
        else        v = w0[co * 625 + k3i * 125 + k4i * 25 + k1o * 5 + k2o];
    }
    wpk0[idx] = (__bf16)v;
}

__global__ __launch_bounds__(256)
void pack_wmid(const float* __restrict__ w10, const float* __restrict__ w11,
               __bf16* __restrict__ wpk)
{
    int idx = blockIdx.x * 256 + (int)threadIdx.x;
    if (idx >= 650 * 512) return;
    const int ci  = idx & 15;
    const int m   = (idx >> 4) & 31;
    const int off = idx >> 9;
    const int inner = off % 26, outer = off / 26;
    const int d1 = outer / 5 - 2, d2 = outer % 5 - 2;
    float v = 0.0f;
    if (inner < 25) {
        const int d3 = inner / 5 - 2, d4 = inner % 5 - 2;
        const int co = m & 7;
        const bool isB  = (m & 8)  != 0;
        const bool is11 = (m & 16) != 0;
        if (is11) {
            int k1, k2, k3, k4;
            if (!isB) { k1 = d1 + 2; k2 = d2 + 2; k3 = d3 + 2; k4 = d4 + 2; }
            else      { k1 = d3 + 2; k2 = d4 + 2; k3 = d1 + 2; k4 = d2 + 2; }
            v = w11[((((co * 16 + ci) * 5 + k1) * 5 + k2) * 5 + k3) * 5 + k4];
        } else {
            if (!isB) {
                if (d1 >= -1 && d1 <= 1 && d2 >= -1 && d2 <= 1)
                    v = w10[((((co * 16 + ci) * 3 + (d1 + 1)) * 3 + (d2 + 1)) * 5 + (d3 + 2)) * 5 + (d4 + 2)];
            } else {
                if (d3 >= -1 && d3 <= 1 && d4 >= -1 && d4 <= 1)
                    v = w10[((((co * 16 + ci) * 3 + (d3 + 1)) * 3 + (d4 + 1)) * 5 + (d1 + 2)) * 5 + (d2 + 2)];
            }
        }
    }
    wpk[idx] = (__bf16)v;
}

__global__ __launch_bounds__(256)
void pack_w2f(const float* __restrict__ w2, __bf16* __restrict__ wpk2f)
{
    int idx = blockIdx.x * 256 + (int)threadIdx.x;
    if (idx >= 26 * 64 * 16) return;
    const int ci = idx & 15;
    const int m  = (idx >> 4) & 63;
    const int e  = idx >> 10;
    float v = 0.0f;
    if (e < 25) {
        if (m < 25)
            v = w2[ci * 625 + (m / 5) * 125 + (m % 5) * 25 + (e / 5) * 5 + (e % 5)];
        else if (m >= 32 && m < 57) {
            const int dd = m - 32;
            v = w2[ci * 625 + (e / 5) * 125 + (e % 5) * 25 + (dd / 5) * 5 + (dd % 5)];
        }
    }
    wpk2f[idx] = (__bf16)v;
}

// ---------------------------------------------------------------------------
// Layer 0 MFMA (round-5 version, unchanged).
// ---------------------------------------------------------------------------
__global__ __launch_bounds__(320)
void conv0_mfma(const float* __restrict__ x, const __bf16* __restrict__ wpk0,
                const float* __restrict__ b0, __bf16* __restrict__ y1)
{
    __shared__ __bf16 lds0[4 * LPAD * 8];

    const int tid  = (int)threadIdx.x;
    const int lane = tid & 63;
    const int wave = tid >> 6;
    const int bid  = blockIdx.x;
    const int o2 = bid % TS, o1 = (bid / TS) % TS, n = bid / TS2;

    for (int i = tid; i < 4 * LPAD * 8 / 2; i += 320) ((int*)lds0)[i] = 0;
    __syncthreads();

    for (int c = tid; c < 25 * TS2; c += 320) {
        const int pl = c / TS2, pt = c % TS2;
        const int i1 = o1 + pl / 5 - 2, i2 = o2 + pl % 5 - 2;
        if (i1 >= 0 && i1 < TS && i2 >= 0 && i2 < TS) {
            const float v = x[(size_t)((n * TS + i1) * TS + i2) * TS2 + pt];
            const int L = (pt / TS + 2) * 24 + (pt % TS + 2);
            lds0[((pl >> 3) * LPAD + L) * 8 + (pl & 7)] = (__bf16)v;
        }
    }
    __syncthreads();

    const int mrow = lane & 15;
    const int sub  = lane >> 4;

    int sb[5];
#pragma unroll
    for (int i = 0; i < 5; ++i) {
        const int p = (wave * 5 + i) * 16 + mrow;
        sb[i] = (sub * LPAD + (p / TS + 2) * 24 + (p % TS + 2)) * 8;
    }

    f32x4 acc0[5], acc1[5];
#pragma unroll
    for (int i = 0; i < 5; ++i) {
        acc0[i] = (f32x4){0.f, 0.f, 0.f, 0.f};
        acc1[i] = (f32x4){0.f, 0.f, 0.f, 0.f};
    }

    bf16x8 a0 = *(const bf16x8*)(wpk0 + (size_t)mrow * 32 + sub * 8);
    bf16x8 a1 = *(const bf16x8*)(wpk0 + (size_t)(16 + mrow) * 32 + sub * 8);
    for (int e = 0; e < 25; ++e) {
        bf16x8 na0 = a0, na1 = a1;
        if (e < 24) {
            na0 = *(const bf16x8*)(wpk0 + ((size_t)((e + 1) * 32 + mrow)) * 32 + sub * 8);
            na1 = *(const bf16x8*)(wpk0 + ((size_t)((e + 1) * 32 + 16 + mrow)) * 32 + sub * 8);
        }
        const int delta = ((e / 5 - 2) * 24 + (e % 5 - 2)) * 8;
#pragma unroll
        for (int i = 0; i < 5; ++i) {
            bf16x8 bfr = *(const bf16x8*)(&lds0[sb[i] + delta]);
            acc0[i] = MFMA16(a0, bfr, acc0[i]);
            acc1[i] = MFMA16(a1, bfr, acc1[i]);
        }
        a0 = na0; a1 = na1;
    }

    const f32x4 bv = *(const f32x4*)(b0 + sub * 4);
#pragma unroll
    for (int i = 0; i < 5; ++i) {
        const int p = (wave * 5 + i) * 16 + mrow;
        bf16x4 pk;
#pragma unroll
        for (int r = 0; r < 4; ++r)
            pk[r] = (__bf16)(relu_f(acc0[i][r] + bv[r]) + relu_f(acc1[i][r] + bv[r]));
        *(bf16x4*)(y1 + ((size_t)bid * TS2 + p) * 16 + sub * 4) = pk;
    }
}

// ---------------------------------------------------------------------------
// Fused layers 10+11 MFMA: EXACT round-3 structure (best measured: 406 us,
// VGPR 48, ~2 blocks/CU) + bijective XCD bid-swizzle (round-4-proven FETCH
// reduction).  Plain [L][16ci] LDS layout, double-buffered, 1 barrier/plane.
// ---------------------------------------------------------------------------
__global__ __launch_bounds__(320)
void conv4d_mid_mfma(const __bf16* __restrict__ y1, const __bf16* __restrict__ wpk,
                     const float* __restrict__ b10, const float* __restrict__ b11,
                     __bf16* __restrict__ y2)
{
    __shared__ __bf16 lds[2][9216];   // [24][24][16ci] x2

    const int tid  = (int)threadIdx.x;
    const int lane = tid & 63;
    const int wave = tid >> 6;
    // XCD swizzle: 1600 blocks = 8 XCDs x 200 contiguous tiles (bijective)
    const int bid0 = blockIdx.x;
    const int bid  = (bid0 & 7) * 200 + (bid0 >> 3);
    const int o2 = bid % TS, o1 = (bid / TS) % TS, n = bid / TS2;

    for (int i = tid; i < 9216; i += 320) ((int*)lds)[i] = 0;

    const int mrow = lane & 15;
    const int sub  = lane >> 4;
    const int ci0  = (sub & 1) * 8;
    const int aoff = (sub >> 1) * 512 + mrow * 16 + ci0;

    int sbase[5];
#pragma unroll
    for (int i = 0; i < 5; ++i) {
        const int p  = (wave * 5 + i) * 16 + mrow;
        sbase[i] = ((p / TS + 2) * 24 + (p % TS + 2)) * 16 + ci0;
    }

    f32x4 acc[5][2];
#pragma unroll
    for (int i = 0; i < 5; ++i) {
        acc[i][0] = (f32x4){0.f, 0.f, 0.f, 0.f};
        acc[i][1] = (f32x4){0.f, 0.f, 0.f, 0.f};
    }

    __syncthreads();

    int buf = 0;
    for (int d1 = -2; d1 <= 2; ++d1) {
        const int i1 = o1 + d1;
        if (i1 < 0 || i1 >= TS) continue;
        for (int d2 = -2; d2 <= 2; ++d2) {
            const int i2 = o2 + d2;
            if (i2 < 0 || i2 >= TS) continue;

            const __bf16* src = y1 + (size_t)((n * TS + i1) * TS + i2) * TS2 * 16;
            for (int c = tid; c < 800; c += 320) {
                const int h = c / 40, rem = c % 40;
                int4v v = *(const int4v*)(src + c * 8);
                *(int4v*)(&lds[buf][((h + 2) * 24 + 2) * 16 + rem * 8]) = v;
            }
            __syncthreads();
            // single barrier per plane is safe with double buffering

            const int outer = (d1 + 2) * 5 + (d2 + 2);
            const __bf16* wbase = wpk + (size_t)outer * 26 * 512;

            bf16x8 a0 = *(const bf16x8*)(wbase + aoff);
            bf16x8 a1 = *(const bf16x8*)(wbase + aoff + 256);
            for (int ic = 0; ic < 13; ++ic) {
                bf16x8 na0 = a0, na1 = a1;
                if (ic < 12) {
                    na0 = *(const bf16x8*)(wbase + (ic + 1) * 1024 + aoff);
                    na1 = *(const bf16x8*)(wbase + (ic + 1) * 1024 + aoff + 256);
                }
                const int e = 2 * ic + (sub >> 1);
                int d3 = 0, d4 = 0;
                if (e < 25) { d3 = e / 5 - 2; d4 = e % 5 - 2; }
                const int delta = (d3 * 24 + d4) * 16;
#pragma unroll
                for (int i = 0; i < 5; ++i) {
                    bf16x8 bfr = *(const bf16x8*)(&lds[buf][sbase[i] + delta]);
                    acc[i][0] = MFMA16(a0, bfr, acc[i][0]);
                    acc[i][1] = MFMA16(a1, bfr, acc[i][1]);
                }
                a0 = na0; a1 = na1;
            }
            buf ^= 1;
        }
    }

    // epilogue -> interleaved bf16 [p][ch]; combine A/B variants via lane^32
    const size_t base = (size_t)bid * TS2 * 16;
#pragma unroll
    for (int i = 0; i < 5; ++i) {
        const int p = (wave * 5 + i) * 16 + mrow;
#pragma unroll
        for (int mt = 0; mt < 2; ++mt) {
            const float* bs = mt ? b11 : b10;
            const f32x4 bv = *(const f32x4*)(bs + (sub & 1) * 4);
            bf16x4 pk;
#pragma unroll
            for (int r = 0; r < 4; ++r) {
                float v = relu_f(acc[i][mt][r] + bv[r]);
                float o = v + __shfl_xor(v, 32);
                pk[r] = (__bf16)o;
            }
            if (lane < 32)
                *(bf16x4*)(y2 + base + (size_t)p * 16 + mt * 8 + (sub & 1) * 4) = pk;
        }
    }
}

// ---------------------------------------------------------------------------
// Layer 2 pass 1 (round-5 version, unchanged).
// ---------------------------------------------------------------------------
__global__ __launch_bounds__(320)
void conv2t_mfma(const __bf16* __restrict__ y2, const __bf16* __restrict__ wpk2f,
                 int n0, __bf16* __restrict__ t)
{
    __shared__ __bf16 lds[2 * LPAD * 8];

    const int tid  = (int)threadIdx.x;
    const int lane = tid & 63;
    const int wave = tid >> 6;
    const int bid = blockIdx.x;
    const int q2 = bid % TS, q1 = (bid / TS) % TS, nl = bid / TS2;

    for (int i = tid; i < 2 * LPAD * 8 / 2; i += 320) ((int*)lds)[i] = 0;
    __syncthreads();

    const __bf16* src = y2 + (size_t)(((n0 + nl) * TS + q1) * TS + q2) * TS2 * 16;
    for (int c = tid; c < 800; c += 320) {
        const int h = c / 40, rem = c % 40;
        const int w = rem >> 1, cb = rem & 1;
        int4v v = *(const int4v*)(src + c * 8);
        *(int4v*)(&lds[(cb * LPAD + (h + 2) * 24 + 2 + w) * 8]) = v;
    }
    __syncthreads();

    const int mrow = lane & 15;
    const int sub  = lane >> 4;

    int sbase[5];
#pragma unroll
    for (int i = 0; i < 5; ++i) {
        const int p  = (wave * 5 + i) * 16 + mrow;
        sbase[i] = ((sub & 1) * LPAD + (p / TS + 2) * 24 + (p % TS + 2)) * 8;
    }

    f32x4 acc[5][4];
#pragma unroll
    for (int i = 0; i < 5; ++i)
#pragma unroll
        for (int mt = 0; mt < 4; ++mt)
            acc[i][mt] = (f32x4){0.f, 0.f, 0.f, 0.f};

    for (int ic = 0; ic < 13; ++ic) {
        const int e = 2 * ic + (sub >> 1);
        int d3 = 0, d4 = 0;
        if (e < 25) { d3 = e / 5 - 2; d4 = e % 5 - 2; }
        const int delta = (d3 * 24 + d4) * 8;
        const __bf16* abase = wpk2f + ((size_t)e * 64 + mrow) * 16 + (sub & 1) * 8;
        bf16x8 a0 = *(const bf16x8*)(abase);
        bf16x8 a1 = *(const bf16x8*)(abase + 256);
        bf16x8 a2 = *(const bf16x8*)(abase + 512);
        bf16x8 a3 = *(const bf16x8*)(abase + 768);
#pragma unroll
        for (int i = 0; i < 5; ++i) {
            bf16x8 bfr = *(const bf16x8*)(&lds[sbase[i] + delta]);
            acc[i][0] = MFMA16(a0, bfr, acc[i][0]);
            acc[i][1] = MFMA16(a1, bfr, acc[i][1]);
            acc[i][2] = MFMA16(a2, bfr, acc[i][2]);
            acc[i][3] = MFMA16(a3, bfr, acc[i][3]);
        }
    }

    __bf16* tb = t + (size_t)((nl * TS + q1) * TS + q2) * (50 * TS2);
#pragma unroll
    for (int i = 0; i < 5; ++i) {
        const int p = (wave * 5 + i) * 16 + mrow;
#pragma unroll
        for (int mt = 0; mt < 4; ++mt) {
#pragma unroll
            for (int r = 0; r < 4; ++r) {
                const int gm = mt * 16 + sub * 4 + r;
                int m50 = -1;
                if (gm < 25) m50 = gm;
                else if (gm >= 32 && gm < 57) m50 = gm - 7;
                if (m50 >= 0) tb[m50 * TS2 + p] = (__bf16)acc[i][mt][r];
            }
        }
    }
}

// ---------------------------------------------------------------------------
// Layer 2 pass 2 (unchanged).
// ---------------------------------------------------------------------------
__global__ __launch_bounds__(448)
void conv2_sum(const __bf16* __restrict__ t, const float* __restrict__ b2,
               int n0, float* __restrict__ out)
{
    const int tid = (int)threadIdx.x;
    if (tid >= TS2) return;
    const int bid = blockIdx.x;
    const int o2 = bid % TS, o1 = (bid / TS) % TS, nl = bid / TS2;

    float accA = 0.0f, accB = 0.0f;
    for (int dd = 0; dd < 25; ++dd) {
        const int q1 = o1 + dd / 5 - 2, q2 = o2 + dd % 5 - 2;
        if (q1 < 0 || q1 >= TS || q2 < 0 || q2 >= TS) continue;
        const __bf16* tb = t + (size_t)((nl * TS + q1) * TS + q2) * (50 * TS2) + tid;
        accA += (float)tb[dd * TS2];
        accB += (float)tb[(25 + dd) * TS2];
    }
    const float bias = b2[0];
    out[(size_t)(n0 + nl) * (TS2 * (size_t)TS2) + (size_t)(o1 * TS + o2) * TS2 + tid] =
        relu_f(accA + bias) + relu_f(accB + bias);
}

// ---------------------------------------------------------------------------
extern "C" void kernel_launch(void* const* d_in, const int* in_sizes, int n_in,
                              void* d_out, int out_size, void* d_ws, size_t ws_size,
                              hipStream_t stream)
{
    const float* x   = (const float*)d_in[0];
    const float* w0  = (const float*)d_in[1];
    const float* b0  = (const float*)d_in[2];
    const float* w10 = (const float*)d_in[3];
    const float* b10 = (const float*)d_in[4];
    const float* w11 = (const float*)d_in[5];
    const float* b11 = (const float*)d_in[6];
    const float* w2  = (const float*)d_in[7];
    const float* b2  = (const float*)d_in[8];
    float* out = (float*)d_out;

    // ws: y1 20.5MB | y2 20.5MB | t 32MB (2-image chunk) | packs ~0.8MB
    __bf16* y1    = (__bf16*)d_ws;
    __bf16* y2    = y1 + (size_t)10240000;
    __bf16* tbuf  = y2 + (size_t)10240000;
    __bf16* wpkm  = tbuf + (size_t)16000000;
    __bf16* wpk0  = wpkm + 650 * 512;
    __bf16* wpk2f = wpk0 + 25 * 32 * 32;

    dim3 blk320(320), blk256(256), blk448(448);

    pack_w0  <<<dim3((25600 + 255) / 256),  blk256, 0, stream>>>(w0, wpk0);
    pack_wmid<<<dim3((332800 + 255) / 256), blk256, 0, stream>>>(w10, w11, wpkm);
    pack_w2f <<<dim3((26624 + 255) / 256),  blk256, 0, stream>>>(w2, wpk2f);

    conv0_mfma     <<<dim3(4 * TS * TS), blk320, 0, stream>>>(x, wpk0, b0, y1);
    conv4d_mid_mfma<<<dim3(1600),        blk320, 0, stream>>>(y1, wpkm, b10, b11, y2);

    for (int n0 = 0; n0 < 4; n0 += 2) {
        conv2t_mfma<<<dim3(800), blk320, 0, stream>>>(y2, wpk2f, n0, tbuf);
        conv2_sum  <<<dim3(800), blk448, 0, stream>>>(tbuf, b2, n0, out);
    }
}